// Round 3
// baseline (7360.546 us; speedup 1.0000x reference)
//
#include <hip/hip_runtime.h>
#include <math.h>

namespace {

constexpr int B  = 4;
constexpr int C  = 512;     // qk_dim == v_dim
constexpr int L  = 4096;    // N == M
constexpr float EPSI = 1e-5f;

// ---------------- K1: per-(b,ch) mean / rstd for q, k, c ----------------
__global__ __launch_bounds__(256) void row_stats_kernel(
    const float* __restrict__ q, const float* __restrict__ k,
    const float* __restrict__ c, float* __restrict__ stats) {
  int row = blockIdx.x;                       // 0..6143 = arr*2048 + b*512 + ch
  const float* base = (row < 2048) ? q : (row < 4096 ? k : c);
  int r = row & 2047;
  const float4* x4 = (const float4*)(base + (size_t)r * L);
  float s = 0.f, ss = 0.f;
  for (int i = threadIdx.x; i < L / 4; i += 256) {
    float4 v = x4[i];
    s  += v.x + v.y + v.z + v.w;
    ss += v.x * v.x + v.y * v.y + v.z * v.z + v.w * v.w;
  }
  #pragma unroll
  for (int off = 32; off > 0; off >>= 1) {
    s  += __shfl_down(s, off, 64);
    ss += __shfl_down(ss, off, 64);
  }
  __shared__ float sh[8];
  int wid = threadIdx.x >> 6, lid = threadIdx.x & 63;
  if (lid == 0) { sh[wid * 2] = s; sh[wid * 2 + 1] = ss; }
  __syncthreads();
  if (threadIdx.x == 0) {
    float S  = sh[0] + sh[2] + sh[4] + sh[6];
    float SS = sh[1] + sh[3] + sh[5] + sh[7];
    float mean = S * (1.f / L);
    float var  = SS * (1.f / L) - mean * mean;
    stats[2 * row]     = mean;
    stats[2 * row + 1] = rsqrtf(var + EPSI);
  }
}

// ---------------- K2: projection GEMM out[o,n] = sum_c W[o,c]*xn[c,n] + b[o] -
// 64x64 tile, K-tile 16, 4x4 micro. Optionally instance-norms the input on
// load (NORM).
template<bool NORM>
__global__ __launch_bounds__(256) void proj_kernel(
    const float* __restrict__ W, const float* __restrict__ bias,
    const float* __restrict__ X, const float* __restrict__ st,
    float* __restrict__ out) {
  int b = blockIdx.z;
  const float* x = X + (size_t)b * C * L;
  float* o = out + (size_t)b * C * L;
  const float* stb = st + (size_t)b * C * 2;
  int n0 = blockIdx.x * 64;
  int o0 = blockIdx.y * 64;
  __shared__ float As[64][17];   // W[o][k]
  __shared__ float Bs[16][68];   // xn[k][n]
  int t = threadIdx.x;
  int tx = t & 15, ty = t >> 4;
  float acc[4][4] = {};
  for (int k0 = 0; k0 < C; k0 += 16) {
    {
      int row = t >> 2, col = (t & 3) * 4;
      float4 v = *(const float4*)(W + (size_t)(o0 + row) * C + k0 + col);
      As[row][col] = v.x; As[row][col + 1] = v.y;
      As[row][col + 2] = v.z; As[row][col + 3] = v.w;
    }
    {
      int row = t >> 4, col = (t & 15) * 4;
      int cc = k0 + row;
      float4 v = *(const float4*)(x + (size_t)cc * L + n0 + col);
      if (NORM) {
        float mu = stb[2 * cc], rs = stb[2 * cc + 1];
        v.x = (v.x - mu) * rs; v.y = (v.y - mu) * rs;
        v.z = (v.z - mu) * rs; v.w = (v.w - mu) * rs;
      }
      *(float4*)&Bs[row][col] = v;
    }
    __syncthreads();
    #pragma unroll
    for (int kk = 0; kk < 16; kk++) {
      float a[4];
      #pragma unroll
      for (int i = 0; i < 4; i++) a[i] = As[ty * 4 + i][kk];
      float4 b4 = *(const float4*)&Bs[kk][tx * 4];
      float bb[4] = {b4.x, b4.y, b4.z, b4.w};
      #pragma unroll
      for (int i = 0; i < 4; i++)
        #pragma unroll
        for (int j = 0; j < 4; j++) acc[i][j] += a[i] * bb[j];
    }
    __syncthreads();
  }
  #pragma unroll
  for (int i = 0; i < 4; i++) {
    int oo = o0 + ty * 4 + i;
    float bv = bias[oo];
    *(float4*)(o + (size_t)oo * L + n0 + tx * 4) =
        make_float4(acc[i][0] + bv, acc[i][1] + bv,
                    acc[i][2] + bv, acc[i][3] + bv);
  }
}

// ---------------- K3: Sc[nl,m] = sum_c qp[c, nbase+nl] * kp[c,m] ------------
__global__ __launch_bounds__(256) void qk_kernel(
    const float* __restrict__ qp, const float* __restrict__ kp,
    float* __restrict__ Sc, int b, int nbase) {
  const float* Aq = qp + (size_t)b * C * L;
  const float* Bk = kp + (size_t)b * C * L;
  int m0 = blockIdx.x * 64;
  int n0 = blockIdx.y * 64;          // local within chunk
  __shared__ float As[16][68];
  __shared__ float Bs[16][68];
  int t = threadIdx.x, tx = t & 15, ty = t >> 4;
  float acc[4][4] = {};
  for (int k0 = 0; k0 < C; k0 += 16) {
    int row = t >> 4, col = (t & 15) * 4;
    *(float4*)&As[row][col] =
        *(const float4*)(Aq + (size_t)(k0 + row) * L + nbase + n0 + col);
    *(float4*)&Bs[row][col] =
        *(const float4*)(Bk + (size_t)(k0 + row) * L + m0 + col);
    __syncthreads();
    #pragma unroll
    for (int kk = 0; kk < 16; kk++) {
      float4 a4 = *(const float4*)&As[kk][ty * 4];
      float4 b4 = *(const float4*)&Bs[kk][tx * 4];
      float a[4]  = {a4.x, a4.y, a4.z, a4.w};
      float bb[4] = {b4.x, b4.y, b4.z, b4.w};
      #pragma unroll
      for (int i = 0; i < 4; i++)
        #pragma unroll
        for (int j = 0; j < 4; j++) acc[i][j] += a[i] * bb[j];
    }
    __syncthreads();
  }
  #pragma unroll
  for (int i = 0; i < 4; i++) {
    int n = n0 + ty * 4 + i;
    *(float4*)(Sc + (size_t)n * L + m0 + tx * 4) =
        make_float4(acc[i][0], acc[i][1], acc[i][2], acc[i][3]);
  }
}

// ---------------- K4: in-place row softmax over m (rows of the chunk) -------
__global__ __launch_bounds__(256) void softmax_kernel(float* __restrict__ Sc) {
  size_t row = blockIdx.x;
  float4* s4 = (float4*)(Sc + row * L);
  int t = threadIdx.x;
  float4 v[4];
  #pragma unroll
  for (int j = 0; j < 4; j++) v[j] = s4[t + 256 * j];
  float mx = -3.0e38f;
  #pragma unroll
  for (int j = 0; j < 4; j++)
    mx = fmaxf(mx, fmaxf(fmaxf(v[j].x, v[j].y), fmaxf(v[j].z, v[j].w)));
  #pragma unroll
  for (int off = 32; off > 0; off >>= 1) mx = fmaxf(mx, __shfl_down(mx, off, 64));
  __shared__ float sh[8];
  __shared__ float bc[2];
  int wid = t >> 6, lid = t & 63;
  if (lid == 0) sh[wid] = mx;
  __syncthreads();
  if (t == 0) bc[0] = fmaxf(fmaxf(sh[0], sh[1]), fmaxf(sh[2], sh[3]));
  __syncthreads();
  mx = bc[0];
  float sum = 0.f;
  #pragma unroll
  for (int j = 0; j < 4; j++) {
    v[j].x = expf(v[j].x - mx); v[j].y = expf(v[j].y - mx);
    v[j].z = expf(v[j].z - mx); v[j].w = expf(v[j].w - mx);
    sum += v[j].x + v[j].y + v[j].z + v[j].w;
  }
  #pragma unroll
  for (int off = 32; off > 0; off >>= 1) sum += __shfl_down(sum, off, 64);
  if (lid == 0) sh[4 + wid] = sum;
  __syncthreads();
  if (t == 0) bc[1] = 1.f / (sh[4] + sh[5] + sh[6] + sh[7]);
  __syncthreads();
  float inv = bc[1];
  #pragma unroll
  for (int j = 0; j < 4; j++) {
    v[j].x *= inv; v[j].y *= inv; v[j].z *= inv; v[j].w *= inv;
    s4[t + 256 * j] = v[j];
  }
}

// ---------------- K5: PV + finalize ----------------
// mean[v,n]   = sum_m P[nl,m] sp[v,m]
// meansq[v,n] = sum_m P[nl,m] sp[v,m]^2
// out[b,v,n]  = instnorm(c)[b,v,n] * sqrt(relu(meansq - mean^2)) + mean
__global__ __launch_bounds__(256) void pv_fin_kernel(
    const float* __restrict__ P, const float* __restrict__ sp,
    const float* __restrict__ c, const float* __restrict__ stats_c,
    float* __restrict__ out, int b, int nbase) {
  const float* Ab = sp + (size_t)b * C * L;
  int v0 = blockIdx.x * 64;   // 8 tiles; x fastest so same-n0 blocks share P in L2
  int n0 = blockIdx.y * 64;   // local within chunk
  __shared__ float As[64][17]; // sp[v][k]
  __shared__ float Bs[64][17]; // P[nl][k]
  int t = threadIdx.x, tx = t & 15, ty = t >> 4;
  float am[4][4] = {};   // mean acc
  float aq[4][4] = {};   // meansq acc
  for (int m0 = 0; m0 < L; m0 += 16) {
    int row = t >> 2, col = (t & 3) * 4;
    float4 av = *(const float4*)(Ab + (size_t)(v0 + row) * L + m0 + col);
    As[row][col] = av.x; As[row][col + 1] = av.y;
    As[row][col + 2] = av.z; As[row][col + 3] = av.w;
    float4 bv = *(const float4*)(P + (size_t)(n0 + row) * L + m0 + col);
    Bs[row][col] = bv.x; Bs[row][col + 1] = bv.y;
    Bs[row][col + 2] = bv.z; Bs[row][col + 3] = bv.w;
    __syncthreads();
    #pragma unroll
    for (int kk = 0; kk < 16; kk++) {
      float a[4], a2[4], bb[4];
      #pragma unroll
      for (int i = 0; i < 4; i++) { a[i] = As[ty * 4 + i][kk]; a2[i] = a[i] * a[i]; }
      #pragma unroll
      for (int j = 0; j < 4; j++) bb[j] = Bs[tx * 4 + j][kk];
      #pragma unroll
      for (int i = 0; i < 4; i++)
        #pragma unroll
        for (int j = 0; j < 4; j++) {
          am[i][j] += a[i] * bb[j];
          aq[i][j] += a2[i] * bb[j];
        }
    }
    __syncthreads();
  }
  #pragma unroll
  for (int i = 0; i < 4; i++) {
    int v = v0 + ty * 4 + i;
    size_t r = (size_t)b * C + v;
    float mu = stats_c[2 * r], rs = stats_c[2 * r + 1];
    int n = nbase + n0 + tx * 4;
    float4 cv = *(const float4*)(c + r * L + n);
    float me[4] = {am[i][0], am[i][1], am[i][2], am[i][3]};
    float ms[4] = {aq[i][0], aq[i][1], aq[i][2], aq[i][3]};
    float cc[4] = {cv.x, cv.y, cv.z, cv.w};
    float4 o;
    float* op = &o.x;
    #pragma unroll
    for (int j = 0; j < 4; j++)
      op[j] = (cc[j] - mu) * rs * sqrtf(fmaxf(ms[j] - me[j] * me[j], 0.f)) + me[j];
    *(float4*)(out + r * L + n) = o;
  }
}

} // namespace

extern "C" void kernel_launch(void* const* d_in, const int* in_sizes, int n_in,
                              void* d_out, int out_size, void* d_ws, size_t ws_size,
                              hipStream_t stream) {
  const float* q  = (const float*)d_in[0];
  const float* k  = (const float*)d_in[1];
  const float* c  = (const float*)d_in[2];
  const float* s  = (const float*)d_in[3];
  const float* Wq = (const float*)d_in[4];
  const float* bq = (const float*)d_in[5];
  const float* Wk = (const float*)d_in[6];
  const float* bk = (const float*)d_in[7];
  const float* Ws = (const float*)d_in[8];
  const float* bs = (const float*)d_in[9];
  float* out = (float*)d_out;

  float* ws = (float*)d_ws;
  const size_t SZ_P = (size_t)B * C * L;           // 8388608 floats (32 MB)
  float* qp    = ws;                               // [B,512,L]
  float* kp    = ws + SZ_P;                        // [B,512,L]
  float* sp    = ws + 2 * SZ_P;                    // [B,512,L]
  float* stats = ws + 3 * SZ_P;                    // 6144*2 floats
  float* Sbuf  = ws + 3 * SZ_P + 16384;            // [n_chunk, L]
  const float* stats_q = stats;
  const float* stats_k = stats + 2048 * 2;
  const float* stats_c = stats + 4096 * 2;

  // pick largest n_chunk (multiple of 64, pow2 divisor of L) that fits ws_size
  size_t base_bytes = (3 * SZ_P + 16384) * sizeof(float);
  int n_chunk = 1024;
  while (n_chunk > 64 &&
         base_bytes + (size_t)n_chunk * L * sizeof(float) > ws_size)
    n_chunk >>= 1;
  // footprint: 96 MB + 64 KB + n_chunk*16KB  (<= 112 MB at n_chunk=1024)

  row_stats_kernel<<<6144, 256, 0, stream>>>(q, k, c, stats);

  dim3 g2(L / 64, C / 64, B);
  proj_kernel<true ><<<g2, 256, 0, stream>>>(Wq, bq, q, stats_q, qp);
  proj_kernel<true ><<<g2, 256, 0, stream>>>(Wk, bk, k, stats_k, kp);
  proj_kernel<false><<<g2, 256, 0, stream>>>(Ws, bs, s, stats_q, sp);

  for (int b = 0; b < B; b++) {
    for (int nbase = 0; nbase < L; nbase += n_chunk) {
      qk_kernel<<<dim3(L / 64, n_chunk / 64), 256, 0, stream>>>(
          qp, kp, Sbuf, b, nbase);
      softmax_kernel<<<n_chunk, 256, 0, stream>>>(Sbuf);
      pv_fin_kernel<<<dim3(C / 64, n_chunk / 64), 256, 0, stream>>>(
          Sbuf, sp, c, stats_c, out, b, nbase);
    }
  }
}

// Round 5
// 1152.988 us; speedup vs baseline: 6.3839x; 6.3839x over previous
//
#include <hip/hip_runtime.h>
#include <math.h>

namespace {

constexpr int B  = 4;
constexpr int C  = 512;     // qk_dim == v_dim
constexpr int L  = 4096;    // N == M
constexpr float EPSI = 1e-5f;

typedef _Float16 f16x8 __attribute__((ext_vector_type(8)));
typedef short    sv8   __attribute__((ext_vector_type(8)));
typedef float    f32x4 __attribute__((ext_vector_type(4)));

__device__ inline unsigned short hfr(float x) {
  _Float16 h = (_Float16)x;
  return __builtin_bit_cast(unsigned short, h);
}
__device__ inline float h2f(unsigned short u) {
  return (float)__builtin_bit_cast(_Float16, u);
}

// ---------------- K1: per-(b,ch) mean / rstd for q, k, c ----------------
__global__ __launch_bounds__(256) void row_stats_kernel(
    const float* __restrict__ q, const float* __restrict__ k,
    const float* __restrict__ c, float* __restrict__ stats) {
  int row = blockIdx.x;                       // 0..6143 = arr*2048 + b*512 + ch
  const float* base = (row < 2048) ? q : (row < 4096 ? k : c);
  int r = row & 2047;
  const float4* x4 = (const float4*)(base + (size_t)r * L);
  float s = 0.f, ss = 0.f;
  for (int i = threadIdx.x; i < L / 4; i += 256) {
    float4 v = x4[i];
    s  += v.x + v.y + v.z + v.w;
    ss += v.x * v.x + v.y * v.y + v.z * v.z + v.w * v.w;
  }
  #pragma unroll
  for (int off = 32; off > 0; off >>= 1) {
    s  += __shfl_down(s, off, 64);
    ss += __shfl_down(ss, off, 64);
  }
  __shared__ float sh[8];
  int wid = threadIdx.x >> 6, lid = threadIdx.x & 63;
  if (lid == 0) { sh[wid * 2] = s; sh[wid * 2 + 1] = ss; }
  __syncthreads();
  if (threadIdx.x == 0) {
    float S  = sh[0] + sh[2] + sh[4] + sh[6];
    float SS = sh[1] + sh[3] + sh[5] + sh[7];
    float mean = S * (1.f / L);
    float var  = SS * (1.f / L) - mean * mean;
    stats[2 * row]     = mean;
    stats[2 * row + 1] = rsqrtf(var + EPSI);
  }
}

// ------- K2: transpose (+optional instance-norm) fp32[C][L] -> fp16[L][C] ---
template<bool NORM>
__global__ __launch_bounds__(256) void transpose_kernel(
    const float* __restrict__ x, const float* __restrict__ stb,
    unsigned short* __restrict__ xT) {
  __shared__ unsigned short sh[64][66];   // padded: conflict-free column reads
  int t = threadIdx.x;
  int i0 = blockIdx.x * 64, c0 = blockIdx.y * 64;
  #pragma unroll
  for (int rep = 0; rep < 4; rep++) {
    int cl = rep * 16 + (t >> 4);
    int f4 = t & 15;
    float4 v = *(const float4*)(x + (size_t)(c0 + cl) * L + i0 + f4 * 4);
    if (NORM) {
      float mu = stb[2 * (c0 + cl)], rs = stb[2 * (c0 + cl) + 1];
      v.x = (v.x - mu) * rs; v.y = (v.y - mu) * rs;
      v.z = (v.z - mu) * rs; v.w = (v.w - mu) * rs;
    }
    *(ushort2*)&sh[cl][f4 * 4]     = make_ushort2(hfr(v.x), hfr(v.y));
    *(ushort2*)&sh[cl][f4 * 4 + 2] = make_ushort2(hfr(v.z), hfr(v.w));
  }
  __syncthreads();
  #pragma unroll
  for (int rr = 0; rr < 4; rr++) {
    int il = rr * 16 + (t >> 4);
    int cl = (t & 15) * 4;
    ushort4 o;
    o.x = sh[cl][il]; o.y = sh[cl + 1][il];
    o.z = sh[cl + 2][il]; o.w = sh[cl + 3][il];
    *(ushort4*)(xT + (size_t)(i0 + il) * C + c0 + cl) = o;
  }
}

// -------- shared MFMA-GEMM building blocks: 128x128 tile, BK=64, 4 waves ----
// LDS tiles are [row][k], k contiguous (64 fp16 = 128B rows).

__device__ inline void stage_f16(const unsigned short* __restrict__ g,
                                 int row_stride, unsigned short* lds, int t) {
  #pragma unroll
  for (int rep = 0; rep < 4; rep++) {
    int r = rep * 32 + (t >> 3);
    int ch = t & 7;
    uint4 v = *(const uint4*)(g + (size_t)r * row_stride + ch * 8);
    *(uint4*)&lds[r * 64 + ch * 8] = v;
  }
}

__device__ inline void stage_cvt(const float* __restrict__ g,
                                 int row_stride, unsigned short* lds, int t) {
  #pragma unroll
  for (int rep = 0; rep < 8; rep++) {
    int r  = rep * 16 + (t >> 4);
    int f4 = t & 15;
    float4 v = *(const float4*)(g + (size_t)r * row_stride + f4 * 4);
    ushort4 o = make_ushort4(hfr(v.x), hfr(v.y), hfr(v.z), hfr(v.w));
    *(ushort4*)&lds[r * 64 + f4 * 4] = o;
  }
}

__device__ inline void mfma_block(const unsigned short* At, const unsigned short* Bt,
                                  f32x4 acc[4][4], int wm, int wn, int lm, int kq) {
  #pragma unroll
  for (int ks = 0; ks < 2; ks++) {
    f16x8 af[4], bf[4];
    #pragma unroll
    for (int i = 0; i < 4; i++)
      af[i] = __builtin_bit_cast(f16x8,
          *(const sv8*)&At[(wm + i * 16 + lm) * 64 + ks * 32 + kq * 8]);
    #pragma unroll
    for (int j = 0; j < 4; j++)
      bf[j] = __builtin_bit_cast(f16x8,
          *(const sv8*)&Bt[(wn + j * 16 + lm) * 64 + ks * 32 + kq * 8]);
    #pragma unroll
    for (int i = 0; i < 4; i++)
      #pragma unroll
      for (int j = 0; j < 4; j++)
        acc[i][j] = __builtin_amdgcn_mfma_f32_16x16x32_f16(af[i], bf[j], acc[i][j], 0, 0, 0);
  }
}

// ---------------- K3: proj for q/k: outT[i][o] = sum_c xT[i][c]*W[o][c] + b[o]
__global__ __launch_bounds__(256) void proj_qk_kernel(
    const unsigned short* __restrict__ xT, const float* __restrict__ W,
    const float* __restrict__ bias, unsigned short* __restrict__ outT) {
  __shared__ __align__(16) unsigned short At[128 * 64];
  __shared__ __align__(16) unsigned short Bt[128 * 64];
  int t = threadIdx.x, lane = t & 63, wv = t >> 6;
  int lm = lane & 15, kq = lane >> 4;
  int wm = (wv >> 1) * 64, wn = (wv & 1) * 64;
  int i0 = blockIdx.x * 128, o0 = blockIdx.y * 128;
  f32x4 acc[4][4] = {};
  for (int kt = 0; kt < C / 64; kt++) {
    __syncthreads();
    stage_f16(xT + (size_t)i0 * C + kt * 64, C, At, t);
    stage_cvt(W  + (size_t)o0 * C + kt * 64, C, Bt, t);
    __syncthreads();
    mfma_block(At, Bt, acc, wm, wn, lm, kq);
  }
  #pragma unroll
  for (int j = 0; j < 4; j++) {
    int o = o0 + wn + j * 16 + lm;
    float bv = bias[o];
    #pragma unroll
    for (int i = 0; i < 4; i++)
      #pragma unroll
      for (int r = 0; r < 4; r++) {
        int irow = i0 + wm + i * 16 + kq * 4 + r;
        outT[(size_t)irow * C + o] = hfr(acc[i][j][r] + bv);
      }
  }
}

// ---------------- K4: proj for s -> 4 planes: vh, vl, sqh, sql --------------
// spp[p][v][j], p-plane stride C*L. val = sum_c Ws[v][c]*sT[j][c] + b[v].
__global__ __launch_bounds__(256) void proj_s_kernel(
    const float* __restrict__ Ws, const unsigned short* __restrict__ sT,
    const float* __restrict__ bias, unsigned short* __restrict__ spp) {
  __shared__ __align__(16) unsigned short At[128 * 64];
  __shared__ __align__(16) unsigned short Bt[128 * 64];
  int t = threadIdx.x, lane = t & 63, wv = t >> 6;
  int lm = lane & 15, kq = lane >> 4;
  int wm = (wv >> 1) * 64, wn = (wv & 1) * 64;
  int j0 = blockIdx.x * 128, v0 = blockIdx.y * 128;
  const size_t PL = (size_t)C * L;
  f32x4 acc[4][4] = {};
  for (int kt = 0; kt < C / 64; kt++) {
    __syncthreads();
    stage_cvt(Ws + (size_t)v0 * C + kt * 64, C, At, t);
    stage_f16(sT + (size_t)j0 * C + kt * 64, C, Bt, t);
    __syncthreads();
    mfma_block(At, Bt, acc, wm, wn, lm, kq);
  }
  #pragma unroll
  for (int i = 0; i < 4; i++)
    #pragma unroll
    for (int r = 0; r < 4; r++) {
      int v = v0 + wm + i * 16 + kq * 4 + r;
      float bv = bias[v];
      #pragma unroll
      for (int j = 0; j < 4; j++) {
        int jc = j0 + wn + j * 16 + lm;
        float val = acc[i][j][r] + bv;
        float sq  = val * val;
        unsigned short vh = hfr(val);
        unsigned short vl = hfr(val - h2f(vh));
        unsigned short qh = hfr(sq);
        unsigned short ql = hfr(sq - h2f(qh));
        size_t off = (size_t)v * L + jc;
        spp[off]          = vh;
        spp[PL + off]     = vl;
        spp[2 * PL + off] = qh;
        spp[3 * PL + off] = ql;
      }
    }
}

// ---------------- K5: QK^T logits: Sc[il][j] = sum_c qpT[ibase+il][c]*kpT[j][c]
__global__ __launch_bounds__(256) void qk_kernel(
    const unsigned short* __restrict__ qpT, const unsigned short* __restrict__ kpT,
    float* __restrict__ Sc, int ibase) {
  __shared__ __align__(16) unsigned short At[128 * 64];
  __shared__ __align__(16) unsigned short Bt[128 * 64];
  int t = threadIdx.x, lane = t & 63, wv = t >> 6;
  int lm = lane & 15, kq = lane >> 4;
  int wm = (wv >> 1) * 64, wn = (wv & 1) * 64;
  int j0 = blockIdx.x * 128, i0 = blockIdx.y * 128;
  f32x4 acc[4][4] = {};
  for (int kt = 0; kt < C / 64; kt++) {
    __syncthreads();
    stage_f16(qpT + (size_t)(ibase + i0) * C + kt * 64, C, At, t);
    stage_f16(kpT + (size_t)j0 * C + kt * 64, C, Bt, t);
    __syncthreads();
    mfma_block(At, Bt, acc, wm, wn, lm, kq);
  }
  #pragma unroll
  for (int i = 0; i < 4; i++)
    #pragma unroll
    for (int r = 0; r < 4; r++) {
      int il = i0 + wm + i * 16 + kq * 4 + r;
      #pragma unroll
      for (int j = 0; j < 4; j++)
        Sc[(size_t)il * L + j0 + wn + j * 16 + lm] = acc[i][j][r];
    }
}

// ---------------- K6: in-place row softmax over j ----------------
__global__ __launch_bounds__(256) void softmax_kernel(float* __restrict__ Sc) {
  size_t row = blockIdx.x;
  float4* s4 = (float4*)(Sc + row * L);
  int t = threadIdx.x;
  float4 v[4];
  #pragma unroll
  for (int j = 0; j < 4; j++) v[j] = s4[t + 256 * j];
  float mx = -3.0e38f;
  #pragma unroll
  for (int j = 0; j < 4; j++)
    mx = fmaxf(mx, fmaxf(fmaxf(v[j].x, v[j].y), fmaxf(v[j].z, v[j].w)));
  #pragma unroll
  for (int off = 32; off > 0; off >>= 1) mx = fmaxf(mx, __shfl_down(mx, off, 64));
  __shared__ float sh[8];
  __shared__ float bc[2];
  int wid = t >> 6, lid = t & 63;
  if (lid == 0) sh[wid] = mx;
  __syncthreads();
  if (t == 0) bc[0] = fmaxf(fmaxf(sh[0], sh[1]), fmaxf(sh[2], sh[3]));
  __syncthreads();
  mx = bc[0];
  float sum = 0.f;
  #pragma unroll
  for (int j = 0; j < 4; j++) {
    v[j].x = __expf(v[j].x - mx); v[j].y = __expf(v[j].y - mx);
    v[j].z = __expf(v[j].z - mx); v[j].w = __expf(v[j].w - mx);
    sum += v[j].x + v[j].y + v[j].z + v[j].w;
  }
  #pragma unroll
  for (int off = 32; off > 0; off >>= 1) sum += __shfl_down(sum, off, 64);
  if (lid == 0) sh[4 + wid] = sum;
  __syncthreads();
  if (t == 0) bc[1] = 1.f / (sh[4] + sh[5] + sh[6] + sh[7]);
  __syncthreads();
  float inv = bc[1];
  #pragma unroll
  for (int j = 0; j < 4; j++) {
    v[j].x *= inv; v[j].y *= inv; v[j].z *= inv; v[j].w *= inv;
    s4[t + 256 * j] = v[j];
  }
}

// ---------------- K7: PV over 4 planes + fused finalize ----------------
// A-tile rows r: group g=r>>4, plane p=g&3 (0=vh,1=vl,2=sqh,3=sql),
// v = v0 + (g>>2)*16 + (r&15). 32 v-channels x 128 i-positions per block.
// me = acc[0]+acc[1], msq = acc[2]+acc[3] -> in-register finalize.
__global__ __launch_bounds__(256) void pv_fin_kernel(
    const float* __restrict__ P, const unsigned short* __restrict__ spp,
    const float* __restrict__ cb, const float* __restrict__ stc,
    float* __restrict__ outb, int ibase) {
  __shared__ __align__(16) unsigned short At[128 * 64];
  __shared__ __align__(16) unsigned short Bt[128 * 64];
  int t = threadIdx.x, lane = t & 63, wv = t >> 6;
  int lm = lane & 15, kq = lane >> 4;
  int wm = (wv >> 1) * 64, wn = (wv & 1) * 64;
  int v0 = blockIdx.x * 32;     // 32 actual v per block (x4 planes = 128 rows)
  int i0 = blockIdx.y * 128;
  const size_t PL = (size_t)C * L;
  f32x4 acc[4][4] = {};
  for (int kt = 0; kt < L / 64; kt++) {
    __syncthreads();
    #pragma unroll
    for (int rep = 0; rep < 4; rep++) {          // A: 4-plane interleave
      int lr = rep * 32 + (t >> 3);
      int g = lr >> 4;
      int p = g & 3;
      int vr = v0 + ((g >> 2) << 4) + (lr & 15);
      const unsigned short* gp =
          spp + (size_t)p * PL + (size_t)vr * L + kt * 64 + (t & 7) * 8;
      *(uint4*)&At[lr * 64 + (t & 7) * 8] = *(const uint4*)gp;
    }
    stage_cvt(P + (size_t)i0 * L + kt * 64, L, Bt, t);
    __syncthreads();
    mfma_block(At, Bt, acc, wm, wn, lm, kq);
  }
  #pragma unroll
  for (int r = 0; r < 4; r++) {
    int v = v0 + (wm >> 2) + kq * 4 + r;         // wm=0 -> +0, wm=64 -> +16
    float mu = stc[2 * v], rs = stc[2 * v + 1];
    #pragma unroll
    for (int j = 0; j < 4; j++) {
      int ipos = ibase + i0 + wn + j * 16 + lm;
      float me = acc[0][j][r] + acc[1][j][r];
      float ms = acc[2][j][r] + acc[3][j][r];
      float sd = sqrtf(fmaxf(ms - me * me, 0.f));
      float cv = cb[(size_t)v * L + ipos];
      outb[(size_t)v * L + ipos] = (cv - mu) * rs * sd + me;
    }
  }
}

} // namespace

extern "C" void kernel_launch(void* const* d_in, const int* in_sizes, int n_in,
                              void* d_out, int out_size, void* d_ws, size_t ws_size,
                              hipStream_t stream) {
  const float* q  = (const float*)d_in[0];
  const float* k  = (const float*)d_in[1];
  const float* c  = (const float*)d_in[2];
  const float* s  = (const float*)d_in[3];
  const float* Wq = (const float*)d_in[4];
  const float* bq = (const float*)d_in[5];
  const float* Wk = (const float*)d_in[6];
  const float* bk = (const float*)d_in[7];
  const float* Ws = (const float*)d_in[8];
  const float* bs = (const float*)d_in[9];
  float* out = (float*)d_out;

  // workspace layout (bytes):
  //   qpT [B][L][C] f16 : 16 MB      @ 0
  //   kpT [B][L][C] f16 : 16 MB      @ 16777216
  //   spp [B][4][C][L]  : 64 MB      @ 33554432
  //   stats 6144*2 fp32 : 48 KB      @ 100663296
  //   scratch (qT/kT/sT transposes OR Sc chunk)  @ 100712448
  char* wsb = (char*)d_ws;
  unsigned short* qpT = (unsigned short*)wsb;
  unsigned short* kpT = (unsigned short*)(wsb + 16777216);
  unsigned short* spp = (unsigned short*)(wsb + 33554432);
  float* stats        = (float*)(wsb + 100663296);
  char* scr           = wsb + 100712448;
  unsigned short* qT  = (unsigned short*)scr;                // per-b [L][C]
  unsigned short* kT  = qT + (size_t)L * C;
  unsigned short* sT  = kT + (size_t)L * C;
  float* Sc           = (float*)scr;                         // [n_ch][L] fp32

  size_t avail = ws_size > 100712448ULL ? ws_size - 100712448ULL : 0;
  int n_ch = 128;
  const int cands[5] = {4096, 2048, 1024, 512, 256};
  for (int ci = 0; ci < 5; ci++)
    if ((size_t)cands[ci] * L * 4 <= avail) { n_ch = cands[ci]; break; }

  row_stats_kernel<<<6144, 256, 0, stream>>>(q, k, c, stats);

  const size_t sppB = (size_t)4 * C * L;   // per-batch spp stride (elements)
  for (int b = 0; b < B; b++) {
    transpose_kernel<true ><<<dim3(64, 8), 256, 0, stream>>>(
        q + (size_t)b * C * L, stats + (size_t)b * C * 2, qT);
    transpose_kernel<true ><<<dim3(64, 8), 256, 0, stream>>>(
        k + (size_t)b * C * L, stats + 4096 + (size_t)b * C * 2, kT);
    transpose_kernel<false><<<dim3(64, 8), 256, 0, stream>>>(
        s + (size_t)b * C * L, nullptr, sT);
    proj_qk_kernel<<<dim3(32, 4), 256, 0, stream>>>(qT, Wq, bq, qpT + (size_t)b * L * C);
    proj_qk_kernel<<<dim3(32, 4), 256, 0, stream>>>(kT, Wk, bk, kpT + (size_t)b * L * C);
    proj_s_kernel <<<dim3(32, 4), 256, 0, stream>>>(Ws, sT, bs, spp + (size_t)b * sppB);
  }

  for (int b = 0; b < B; b++) {
    for (int ibase = 0; ibase < L; ibase += n_ch) {
      qk_kernel<<<dim3(32, n_ch / 128), 256, 0, stream>>>(
          qpT + (size_t)b * L * C, kpT + (size_t)b * L * C, Sc, ibase);
      softmax_kernel<<<n_ch, 256, 0, stream>>>(Sc);
      pv_fin_kernel<<<dim3(16, n_ch / 128), 256, 0, stream>>>(
          Sc, spp + (size_t)b * sppB, c + (size_t)b * C * L,
          stats + 8192 + (size_t)b * C * 2, out + (size_t)b * C * L, ibase);
    }
  }
}

// Round 6
// 960.040 us; speedup vs baseline: 7.6669x; 1.2010x over previous
//
#include <hip/hip_runtime.h>
#include <math.h>

namespace {

constexpr int B  = 4;
constexpr int C  = 512;     // qk_dim == v_dim
constexpr int L  = 4096;    // N == M
constexpr int LDST = 72;    // LDS row stride (fp16 elems): 144B -> conflict-free b128
constexpr float EPSI = 1e-5f;

typedef _Float16 f16x8 __attribute__((ext_vector_type(8)));
typedef short    sv8   __attribute__((ext_vector_type(8)));
typedef float    f32x4 __attribute__((ext_vector_type(4)));

__device__ inline unsigned short hfr(float x) {
  _Float16 h = (_Float16)x;
  return __builtin_bit_cast(unsigned short, h);
}
__device__ inline float h2f(unsigned short u) {
  return (float)__builtin_bit_cast(_Float16, u);
}

// ---------------- K1: per-(b,ch) mean / rstd for q, k, c ----------------
__global__ __launch_bounds__(256) void row_stats_kernel(
    const float* __restrict__ q, const float* __restrict__ k,
    const float* __restrict__ c, float* __restrict__ stats) {
  int row = blockIdx.x;                       // 0..6143 = arr*2048 + b*512 + ch
  const float* base = (row < 2048) ? q : (row < 4096 ? k : c);
  int r = row & 2047;
  const float4* x4 = (const float4*)(base + (size_t)r * L);
  float s = 0.f, ss = 0.f;
  for (int i = threadIdx.x; i < L / 4; i += 256) {
    float4 v = x4[i];
    s  += v.x + v.y + v.z + v.w;
    ss += v.x * v.x + v.y * v.y + v.z * v.z + v.w * v.w;
  }
  #pragma unroll
  for (int off = 32; off > 0; off >>= 1) {
    s  += __shfl_down(s, off, 64);
    ss += __shfl_down(ss, off, 64);
  }
  __shared__ float sh[8];
  int wid = threadIdx.x >> 6, lid = threadIdx.x & 63;
  if (lid == 0) { sh[wid * 2] = s; sh[wid * 2 + 1] = ss; }
  __syncthreads();
  if (threadIdx.x == 0) {
    float S  = sh[0] + sh[2] + sh[4] + sh[6];
    float SS = sh[1] + sh[3] + sh[5] + sh[7];
    float mean = S * (1.f / L);
    float var  = SS * (1.f / L) - mean * mean;
    stats[2 * row]     = mean;
    stats[2 * row + 1] = rsqrtf(var + EPSI);
  }
}

// ------- K2: transpose (+optional instance-norm) fp32[C][L] -> fp16[L][C] ---
template<bool NORM>
__global__ __launch_bounds__(256) void transpose_kernel(
    const float* __restrict__ x, const float* __restrict__ stb,
    unsigned short* __restrict__ xT) {
  __shared__ unsigned short sh[64][66];   // padded: conflict-free column reads
  int t = threadIdx.x;
  int i0 = blockIdx.x * 64, c0 = blockIdx.y * 64;
  #pragma unroll
  for (int rep = 0; rep < 4; rep++) {
    int cl = rep * 16 + (t >> 4);
    int f4 = t & 15;
    float4 v = *(const float4*)(x + (size_t)(c0 + cl) * L + i0 + f4 * 4);
    if (NORM) {
      float mu = stb[2 * (c0 + cl)], rs = stb[2 * (c0 + cl) + 1];
      v.x = (v.x - mu) * rs; v.y = (v.y - mu) * rs;
      v.z = (v.z - mu) * rs; v.w = (v.w - mu) * rs;
    }
    *(ushort2*)&sh[cl][f4 * 4]     = make_ushort2(hfr(v.x), hfr(v.y));
    *(ushort2*)&sh[cl][f4 * 4 + 2] = make_ushort2(hfr(v.z), hfr(v.w));
  }
  __syncthreads();
  #pragma unroll
  for (int rr = 0; rr < 4; rr++) {
    int il = rr * 16 + (t >> 4);
    int cl = (t & 15) * 4;
    ushort4 o;
    o.x = sh[cl][il]; o.y = sh[cl + 1][il];
    o.z = sh[cl + 2][il]; o.w = sh[cl + 3][il];
    *(ushort4*)(xT + (size_t)(i0 + il) * C + c0 + cl) = o;
  }
}

// -------- shared MFMA-GEMM building blocks: 128x128 tile, BK=64, 4 waves ----
// LDS tiles are [row][k], k contiguous, row stride LDST=72 (conflict-free).

__device__ inline void stage_f16(const unsigned short* __restrict__ g,
                                 int row_stride, unsigned short* lds, int t) {
  #pragma unroll
  for (int rep = 0; rep < 4; rep++) {
    int r = rep * 32 + (t >> 3);
    int ch = t & 7;
    uint4 v = *(const uint4*)(g + (size_t)r * row_stride + ch * 8);
    *(uint4*)&lds[r * LDST + ch * 8] = v;
  }
}

__device__ inline void stage_cvt(const float* __restrict__ g,
                                 int row_stride, unsigned short* lds, int t) {
  #pragma unroll
  for (int rep = 0; rep < 8; rep++) {
    int r  = rep * 16 + (t >> 4);
    int f4 = t & 15;
    float4 v = *(const float4*)(g + (size_t)r * row_stride + f4 * 4);
    ushort4 o = make_ushort4(hfr(v.x), hfr(v.y), hfr(v.z), hfr(v.w));
    *(ushort4*)&lds[r * LDST + f4 * 4] = o;
  }
}

__device__ inline void mfma_block(const unsigned short* At, const unsigned short* Bt,
                                  f32x4 acc[4][4], int wm, int wn, int lm, int kq) {
  #pragma unroll
  for (int ks = 0; ks < 2; ks++) {
    f16x8 af[4], bf[4];
    #pragma unroll
    for (int i = 0; i < 4; i++)
      af[i] = __builtin_bit_cast(f16x8,
          *(const sv8*)&At[(wm + i * 16 + lm) * LDST + ks * 32 + kq * 8]);
    #pragma unroll
    for (int j = 0; j < 4; j++)
      bf[j] = __builtin_bit_cast(f16x8,
          *(const sv8*)&Bt[(wn + j * 16 + lm) * LDST + ks * 32 + kq * 8]);
    #pragma unroll
    for (int i = 0; i < 4; i++)
      #pragma unroll
      for (int j = 0; j < 4; j++)
        acc[i][j] = __builtin_amdgcn_mfma_f32_16x16x32_f16(af[i], bf[j], acc[i][j], 0, 0, 0);
  }
}

// ---------------- K3: proj for q/k: outT[i][o] = sum_c xT[i][c]*W[o][c] + b[o]
__global__ __launch_bounds__(256) void proj_qk_kernel(
    const unsigned short* __restrict__ xT, const float* __restrict__ W,
    const float* __restrict__ bias, unsigned short* __restrict__ outT) {
  __shared__ __align__(16) unsigned short At[128 * LDST];
  __shared__ __align__(16) unsigned short Bt[128 * LDST];
  int t = threadIdx.x, lane = t & 63, wv = t >> 6;
  int lm = lane & 15, kq = lane >> 4;
  int wm = (wv >> 1) * 64, wn = (wv & 1) * 64;
  int i0 = blockIdx.x * 128, o0 = blockIdx.y * 128;
  f32x4 acc[4][4] = {};
  for (int kt = 0; kt < C / 64; kt++) {
    __syncthreads();
    stage_f16(xT + (size_t)i0 * C + kt * 64, C, At, t);
    stage_cvt(W  + (size_t)o0 * C + kt * 64, C, Bt, t);
    __syncthreads();
    mfma_block(At, Bt, acc, wm, wn, lm, kq);
  }
  #pragma unroll
  for (int j = 0; j < 4; j++) {
    int o = o0 + wn + j * 16 + lm;
    float bv = bias[o];
    #pragma unroll
    for (int i = 0; i < 4; i++)
      #pragma unroll
      for (int r = 0; r < 4; r++) {
        int irow = i0 + wm + i * 16 + kq * 4 + r;
        outT[(size_t)irow * C + o] = hfr(acc[i][j][r] + bv);
      }
  }
}

// ---------------- K4: proj for s -> 4 planes: vh, vl, sqh, sql --------------
// spp[p][v][j], p-plane stride C*L. val = sum_c Ws[v][c]*sT[j][c] + b[v].
__global__ __launch_bounds__(256) void proj_s_kernel(
    const float* __restrict__ Ws, const unsigned short* __restrict__ sT,
    const float* __restrict__ bias, unsigned short* __restrict__ spp) {
  __shared__ __align__(16) unsigned short At[128 * LDST];
  __shared__ __align__(16) unsigned short Bt[128 * LDST];
  int t = threadIdx.x, lane = t & 63, wv = t >> 6;
  int lm = lane & 15, kq = lane >> 4;
  int wm = (wv >> 1) * 64, wn = (wv & 1) * 64;
  int j0 = blockIdx.x * 128, v0 = blockIdx.y * 128;
  const size_t PL = (size_t)C * L;
  f32x4 acc[4][4] = {};
  for (int kt = 0; kt < C / 64; kt++) {
    __syncthreads();
    stage_cvt(Ws + (size_t)v0 * C + kt * 64, C, At, t);
    stage_f16(sT + (size_t)j0 * C + kt * 64, C, Bt, t);
    __syncthreads();
    mfma_block(At, Bt, acc, wm, wn, lm, kq);
  }
  #pragma unroll
  for (int i = 0; i < 4; i++)
    #pragma unroll
    for (int r = 0; r < 4; r++) {
      int v = v0 + wm + i * 16 + kq * 4 + r;
      float bv = bias[v];
      #pragma unroll
      for (int j = 0; j < 4; j++) {
        int jc = j0 + wn + j * 16 + lm;
        float val = acc[i][j][r] + bv;
        float sq  = val * val;
        unsigned short vh = hfr(val);
        unsigned short vl = hfr(val - h2f(vh));
        unsigned short qh = hfr(sq);
        unsigned short ql = hfr(sq - h2f(qh));
        size_t off = (size_t)v * L + jc;
        spp[off]          = vh;
        spp[PL + off]     = vl;
        spp[2 * PL + off] = qh;
        spp[3 * PL + off] = ql;
      }
    }
}

// ---------------- K5: QK^T logits: Sc[il][j] = sum_c qpT[ibase+il][c]*kpT[j][c]
__global__ __launch_bounds__(256) void qk_kernel(
    const unsigned short* __restrict__ qpT, const unsigned short* __restrict__ kpT,
    float* __restrict__ Sc, int ibase) {
  __shared__ __align__(16) unsigned short At[128 * LDST];
  __shared__ __align__(16) unsigned short Bt[128 * LDST];
  int t = threadIdx.x, lane = t & 63, wv = t >> 6;
  int lm = lane & 15, kq = lane >> 4;
  int wm = (wv >> 1) * 64, wn = (wv & 1) * 64;
  int j0 = blockIdx.x * 128, i0 = blockIdx.y * 128;
  f32x4 acc[4][4] = {};
  for (int kt = 0; kt < C / 64; kt++) {
    __syncthreads();
    stage_f16(qpT + (size_t)(ibase + i0) * C + kt * 64, C, At, t);
    stage_f16(kpT + (size_t)j0 * C + kt * 64, C, Bt, t);
    __syncthreads();
    mfma_block(At, Bt, acc, wm, wn, lm, kq);
  }
  #pragma unroll
  for (int i = 0; i < 4; i++)
    #pragma unroll
    for (int r = 0; r < 4; r++) {
      int il = i0 + wm + i * 16 + kq * 4 + r;
      #pragma unroll
      for (int j = 0; j < 4; j++)
        Sc[(size_t)il * L + j0 + wn + j * 16 + lm] = acc[i][j][r];
    }
}

// -------- K6: row softmax over j; reads fp32 logits, writes fp16 probs ------
__global__ __launch_bounds__(256) void softmax_kernel(
    const float* __restrict__ Sc, unsigned short* __restrict__ Ph) {
  size_t row = blockIdx.x;
  const float4* s4 = (const float4*)(Sc + row * L);
  int t = threadIdx.x;
  float4 v[4];
  #pragma unroll
  for (int j = 0; j < 4; j++) v[j] = s4[t + 256 * j];
  float mx = -3.0e38f;
  #pragma unroll
  for (int j = 0; j < 4; j++)
    mx = fmaxf(mx, fmaxf(fmaxf(v[j].x, v[j].y), fmaxf(v[j].z, v[j].w)));
  #pragma unroll
  for (int off = 32; off > 0; off >>= 1) mx = fmaxf(mx, __shfl_down(mx, off, 64));
  __shared__ float sh[8];
  __shared__ float bc[2];
  int wid = t >> 6, lid = t & 63;
  if (lid == 0) sh[wid] = mx;
  __syncthreads();
  if (t == 0) bc[0] = fmaxf(fmaxf(sh[0], sh[1]), fmaxf(sh[2], sh[3]));
  __syncthreads();
  mx = bc[0];
  float sum = 0.f;
  #pragma unroll
  for (int j = 0; j < 4; j++) {
    v[j].x = __expf(v[j].x - mx); v[j].y = __expf(v[j].y - mx);
    v[j].z = __expf(v[j].z - mx); v[j].w = __expf(v[j].w - mx);
    sum += v[j].x + v[j].y + v[j].z + v[j].w;
  }
  #pragma unroll
  for (int off = 32; off > 0; off >>= 1) sum += __shfl_down(sum, off, 64);
  if (lid == 0) sh[4 + wid] = sum;
  __syncthreads();
  if (t == 0) bc[1] = 1.f / (sh[4] + sh[5] + sh[6] + sh[7]);
  __syncthreads();
  float inv = bc[1];
  #pragma unroll
  for (int j = 0; j < 4; j++) {
    ushort4 o = make_ushort4(hfr(v[j].x * inv), hfr(v[j].y * inv),
                             hfr(v[j].z * inv), hfr(v[j].w * inv));
    *(ushort4*)(Ph + row * L + (t + 256 * j) * 4) = o;
  }
}

// ---------------- K7: PV over 4 planes + fused finalize ----------------
// A-tile rows r: group g=r>>4, plane p=g&3 (0=vh,1=vl,2=sqh,3=sql),
// v = v0 + (g>>2)*16 + (r&15). 32 v-channels x 128 i-positions per block.
// me = acc[0]+acc[1], msq = acc[2]+acc[3] -> in-register finalize.
__global__ __launch_bounds__(256) void pv_fin_kernel(
    const unsigned short* __restrict__ Ph, const unsigned short* __restrict__ spp,
    const float* __restrict__ cb, const float* __restrict__ stc,
    float* __restrict__ outb, int ibase) {
  __shared__ __align__(16) unsigned short At[128 * LDST];
  __shared__ __align__(16) unsigned short Bt[128 * LDST];
  int t = threadIdx.x, lane = t & 63, wv = t >> 6;
  int lm = lane & 15, kq = lane >> 4;
  int wm = (wv >> 1) * 64, wn = (wv & 1) * 64;
  int v0 = blockIdx.x * 32;     // 32 actual v per block (x4 planes = 128 rows)
  int i0 = blockIdx.y * 128;
  const size_t PL = (size_t)C * L;
  f32x4 acc[4][4] = {};
  for (int kt = 0; kt < L / 64; kt++) {
    __syncthreads();
    #pragma unroll
    for (int rep = 0; rep < 4; rep++) {          // A: 4-plane interleave
      int lr = rep * 32 + (t >> 3);
      int g = lr >> 4;
      int p = g & 3;
      int vr = v0 + ((g >> 2) << 4) + (lr & 15);
      const unsigned short* gp =
          spp + (size_t)p * PL + (size_t)vr * L + kt * 64 + (t & 7) * 8;
      *(uint4*)&At[lr * LDST + (t & 7) * 8] = *(const uint4*)gp;
    }
    stage_f16(Ph + (size_t)i0 * L + kt * 64, L, Bt, t);
    __syncthreads();
    mfma_block(At, Bt, acc, wm, wn, lm, kq);
  }
  #pragma unroll
  for (int r = 0; r < 4; r++) {
    int v = v0 + (wm >> 2) + kq * 4 + r;         // wm=0 -> +0, wm=64 -> +16
    float mu = stc[2 * v], rs = stc[2 * v + 1];
    #pragma unroll
    for (int j = 0; j < 4; j++) {
      int ipos = ibase + i0 + wn + j * 16 + lm;
      float me = acc[0][j][r] + acc[1][j][r];
      float ms = acc[2][j][r] + acc[3][j][r];
      float sd = sqrtf(fmaxf(ms - me * me, 0.f));
      float cv = cb[(size_t)v * L + ipos];
      outb[(size_t)v * L + ipos] = (cv - mu) * rs * sd + me;
    }
  }
}

} // namespace

extern "C" void kernel_launch(void* const* d_in, const int* in_sizes, int n_in,
                              void* d_out, int out_size, void* d_ws, size_t ws_size,
                              hipStream_t stream) {
  const float* q  = (const float*)d_in[0];
  const float* k  = (const float*)d_in[1];
  const float* c  = (const float*)d_in[2];
  const float* s  = (const float*)d_in[3];
  const float* Wq = (const float*)d_in[4];
  const float* bq = (const float*)d_in[5];
  const float* Wk = (const float*)d_in[6];
  const float* bk = (const float*)d_in[7];
  const float* Ws = (const float*)d_in[8];
  const float* bs = (const float*)d_in[9];
  float* out = (float*)d_out;

  // workspace layout (bytes):
  //   qpT [B][L][C] f16 : 16 MB      @ 0
  //   kpT [B][L][C] f16 : 16 MB      @ 16777216
  //   spp [B][4][C][L]  : 64 MB      @ 33554432
  //   stats 6144*2 fp32 : 48 KB      @ 100663296
  //   scratch @ 100712448: phase1 qT/kT/sT (12 MB) | phase2 Sc fp32 + Ph fp16
  char* wsb = (char*)d_ws;
  unsigned short* qpT = (unsigned short*)wsb;
  unsigned short* kpT = (unsigned short*)(wsb + 16777216);
  unsigned short* spp = (unsigned short*)(wsb + 33554432);
  float* stats        = (float*)(wsb + 100663296);
  char* scr           = wsb + 100712448;
  unsigned short* qT  = (unsigned short*)scr;                // per-b [L][C]
  unsigned short* kT  = qT + (size_t)L * C;
  unsigned short* sT  = kT + (size_t)L * C;

  size_t avail = ws_size > 100712448ULL ? ws_size - 100712448ULL : 0;
  int n_ch = 128;
  const int cands[5] = {4096, 2048, 1024, 512, 256};
  for (int ci = 0; ci < 5; ci++)
    if ((size_t)cands[ci] * L * 6 <= avail) { n_ch = cands[ci]; break; }
  float* Sc          = (float*)scr;                          // [n_ch][L] fp32
  unsigned short* Ph = (unsigned short*)(scr + (size_t)n_ch * L * 4);  // f16

  row_stats_kernel<<<6144, 256, 0, stream>>>(q, k, c, stats);

  const size_t sppB = (size_t)4 * C * L;   // per-batch spp stride (elements)
  for (int b = 0; b < B; b++) {
    transpose_kernel<true ><<<dim3(64, 8), 256, 0, stream>>>(
        q + (size_t)b * C * L, stats + (size_t)b * C * 2, qT);
    transpose_kernel<true ><<<dim3(64, 8), 256, 0, stream>>>(
        k + (size_t)b * C * L, stats + 4096 + (size_t)b * C * 2, kT);
    transpose_kernel<false><<<dim3(64, 8), 256, 0, stream>>>(
        s + (size_t)b * C * L, nullptr, sT);
    proj_qk_kernel<<<dim3(32, 4), 256, 0, stream>>>(qT, Wq, bq, qpT + (size_t)b * L * C);
    proj_qk_kernel<<<dim3(32, 4), 256, 0, stream>>>(kT, Wk, bk, kpT + (size_t)b * L * C);
    proj_s_kernel <<<dim3(32, 4), 256, 0, stream>>>(Ws, sT, bs, spp + (size_t)b * sppB);
  }

  for (int b = 0; b < B; b++) {
    for (int ibase = 0; ibase < L; ibase += n_ch) {
      qk_kernel<<<dim3(32, n_ch / 128), 256, 0, stream>>>(
          qpT + (size_t)b * L * C, kpT + (size_t)b * L * C, Sc, ibase);
      softmax_kernel<<<n_ch, 256, 0, stream>>>(Sc, Ph);
      pv_fin_kernel<<<dim3(16, n_ch / 128), 256, 0, stream>>>(
          Ph, spp + (size_t)b * sppB, c + (size_t)b * C * L,
          stats + 8192 + (size_t)b * C * 2, out + (size_t)b * C * L, ibase);
    }
  }
}